// Round 1
// baseline (448.811 us; speedup 1.0000x reference)
//
#include <hip/hip_runtime.h>
#include <math.h>

#define NEG_SLOPE 0.2f
#define BK_BITS 9
#define BK (1 << BK_BITS)     // 512 dst per bucket -> NB = 196 buckets
#define SBITS 17              // bits for src id (N=100000 < 2^17)
#define SMASK ((1 << SBITS) - 1)
#define CAP 20480             // pairs capacity per bucket (mean 16327, +32 sigma)

__device__ __forceinline__ float lrelu(float x) { return x > 0.f ? x : NEG_SLOPE * x; }

// ==================== init bucket cursors ====================
__global__ void init_bcur(int* __restrict__ bcur, int NB) {
    int i = threadIdx.x;
    if (i < NB) bcur[i] = i * CAP;
}

// ==================== LDS-staged bucketed scatter (unchanged, proven) ====================
__global__ __launch_bounds__(256) void bucket_scatter(const int* __restrict__ src,
                                                      const int* __restrict__ dst,
                                                      int* __restrict__ bcur,
                                                      int* __restrict__ pairs, int E) {
    __shared__ int cnt[256], sc[256], off[256], cur[256], gbase[256];
    __shared__ int lpair[4096];
    __shared__ unsigned char lbkt[4096];
    int t = threadIdx.x;
    cnt[t] = 0;
    __syncthreads();

    int E4 = E >> 2;
    const int4* src4 = (const int4*)src;
    const int4* dst4 = (const int4*)dst;
    int base4 = blockIdx.x * 1024;
    int4 d4[4], s4[4];
    bool val[4];
#pragma unroll
    for (int k = 0; k < 4; k++) {
        int i4 = base4 + k * 256 + t;
        val[k] = (i4 < E4);
        if (val[k]) {
            d4[k] = dst4[i4];
            s4[k] = src4[i4];
            atomicAdd(&cnt[d4[k].x >> BK_BITS], 1);
            atomicAdd(&cnt[d4[k].y >> BK_BITS], 1);
            atomicAdd(&cnt[d4[k].z >> BK_BITS], 1);
            atomicAdd(&cnt[d4[k].w >> BK_BITS], 1);
        }
    }
    int dt = -1, st = 0;
    if (blockIdx.x == gridDim.x - 1) {
        int e = (E4 << 2) + t;
        if (e < E) { dt = dst[e]; st = src[e]; atomicAdd(&cnt[dt >> BK_BITS], 1); }
    }
    __syncthreads();

    sc[t] = cnt[t];
    __syncthreads();
    for (int o = 1; o < 256; o <<= 1) {
        int u = (t >= o) ? sc[t - o] : 0;
        __syncthreads();
        sc[t] += u;
        __syncthreads();
    }
    int excl = (t == 0) ? 0 : sc[t - 1];
    off[t] = excl;
    cur[t] = excl;
    if (cnt[t] > 0) gbase[t] = atomicAdd(&bcur[t], cnt[t]);
    __syncthreads();
    int total = sc[255];

#pragma unroll
    for (int k = 0; k < 4; k++) {
        if (val[k]) {
            int b, slot;
            b = d4[k].x >> BK_BITS; slot = atomicAdd(&cur[b], 1);
            lpair[slot] = ((d4[k].x & (BK - 1)) << SBITS) | s4[k].x; lbkt[slot] = (unsigned char)b;
            b = d4[k].y >> BK_BITS; slot = atomicAdd(&cur[b], 1);
            lpair[slot] = ((d4[k].y & (BK - 1)) << SBITS) | s4[k].y; lbkt[slot] = (unsigned char)b;
            b = d4[k].z >> BK_BITS; slot = atomicAdd(&cur[b], 1);
            lpair[slot] = ((d4[k].z & (BK - 1)) << SBITS) | s4[k].z; lbkt[slot] = (unsigned char)b;
            b = d4[k].w >> BK_BITS; slot = atomicAdd(&cur[b], 1);
            lpair[slot] = ((d4[k].w & (BK - 1)) << SBITS) | s4[k].w; lbkt[slot] = (unsigned char)b;
        }
    }
    if (dt >= 0) {
        int b = dt >> BK_BITS;
        int slot = atomicAdd(&cur[b], 1);
        lpair[slot] = ((dt & (BK - 1)) << SBITS) | st; lbkt[slot] = (unsigned char)b;
    }
    __syncthreads();

    for (int i = t; i < total; i += 256) {
        int b = lbkt[i];
        pairs[gbase[b] + (i - off[b])] = lpair[i];
    }
}

// ==================== fused layer1: per-bucket LDS accumulation ====================
// One block per bucket of 512 dsts. State per dst: al_dst[4] + {Sw,S0,S1}[4 heads]
// = 16 floats -> 32KB LDS. Pairs streamed once; ds_add_f32 scatter-accumulate.
// Self-loop folded into accumulator init. Epilogue fuses W1 -> +b1 -> ELU -> W2.
__global__ __launch_bounds__(1024) void agg1_bucket(
        const int* __restrict__ pairs, const int* __restrict__ bcur,
        const float2* __restrict__ x2,
        const float* __restrict__ W1, const float* __restrict__ asrc,
        const float* __restrict__ adst, const float* __restrict__ b1,
        const float* __restrict__ W2, const float* __restrict__ as2,
        const float* __restrict__ ad2,
        float2* __restrict__ h2, float* __restrict__ al2d, int N) {
    __shared__ float sW[64], sB[32], sW2[64], sP[4], sQ[4], sPd[4], sQd[4], sA2[4];
    __shared__ float4 sAld[BK];          // per-dst al_dst, 4 heads packed (b128 read)
    __shared__ float sAcc[12 * BK];      // [h*BK+d]=Sw, +4*BK=S0, +8*BK=S1
    int t = threadIdx.x;
    int b = blockIdx.x;
    if (t < 64) { sW[t] = W1[t]; sW2[t] = W2[t]; }
    if (t < 32) sB[t] = b1[t];
    if (t < 2) { sA2[t] = as2[t]; sA2[2 + t] = ad2[t]; }
    if (t < 4) {
        float P = 0.f, Q = 0.f, Pd = 0.f, Qd = 0.f;
#pragma unroll
        for (int k = 0; k < 8; k++) {
            int c = t * 8 + k;
            float a = asrc[c], ad_ = adst[c];
            float w0 = W1[c], w1 = W1[32 + c];
            P += w0 * a; Q += w1 * a;
            Pd += w0 * ad_; Qd += w1 * ad_;
        }
        sP[t] = P; sQ[t] = Q; sPd[t] = Pd; sQd[t] = Qd;
    }
    __syncthreads();

    float rP[4], rQ[4];
#pragma unroll
    for (int h = 0; h < 4; h++) { rP[h] = sP[h]; rQ[h] = sQ[h]; }

    int dbase = b << BK_BITS;
    int ndst = min(BK, N - dbase);

    // ---- phase A: init accumulators with self-loop, stash al_dst ----
    if (t < ndst) {
        float2 xd = x2[dbase + t];
        float ald[4];
#pragma unroll
        for (int h = 0; h < 4; h++) {
            ald[h] = xd.x * sPd[h] + xd.y * sQd[h];
            float e = lrelu(fmaf(xd.x, rP[h], fmaf(xd.y, rQ[h], ald[h])));
            float w = __expf(fminf(e, 80.f));
            sAcc[h * BK + t] = w;
            sAcc[4 * BK + h * BK + t] = w * xd.x;
            sAcc[8 * BK + h * BK + t] = w * xd.y;
        }
        sAld[t] = make_float4(ald[0], ald[1], ald[2], ald[3]);
    }
    __syncthreads();

    // ---- phase B: stream pairs once, LDS scatter-accumulate ----
    int lo = b * CAP, hi = bcur[b];
    for (int base = lo + (t << 2); base < hi; base += 4096) {
        int4 p4 = *(const int4*)(pairs + base);   // 16B-aligned (CAP % 4 == 0)
        int pv[4] = {p4.x, p4.y, p4.z, p4.w};
        int nlive = min(hi - base, 4);
        float2 xs[4];
#pragma unroll
        for (int k = 0; k < 4; k++) {
            int s = (k < nlive) ? (pv[k] & SMASK) : 0;
            xs[k] = x2[s];
        }
#pragma unroll
        for (int k = 0; k < 4; k++) {
            if (k < nlive) {
                int dl = pv[k] >> SBITS;
                float4 av = sAld[dl];
                float alh[4] = {av.x, av.y, av.z, av.w};
#pragma unroll
                for (int h = 0; h < 4; h++) {
                    float e = lrelu(fmaf(xs[k].x, rP[h], fmaf(xs[k].y, rQ[h], alh[h])));
                    float w = __expf(fminf(e, 80.f));
                    unsafeAtomicAdd(&sAcc[h * BK + dl], w);
                    unsafeAtomicAdd(&sAcc[4 * BK + h * BK + dl], w * xs[k].x);
                    unsafeAtomicAdd(&sAcc[8 * BK + h * BK + dl], w * xs[k].y);
                }
            }
        }
    }
    __syncthreads();

    // ---- phase C: normalize + fused W1/bias/ELU/W2 epilogue ----
    if (t < ndst) {
        float r[4], S0[4], S1[4];
#pragma unroll
        for (int h = 0; h < 4; h++) {
            float sw = sAcc[h * BK + t];
            r[h] = 1.f / (sw + 1e-16f);
            S0[h] = sAcc[4 * BK + h * BK + t];
            S1[h] = sAcc[8 * BK + h * BK + t];
        }
        float h20 = 0.f, h21 = 0.f;
#pragma unroll
        for (int c = 0; c < 32; c++) {
            int h = c >> 3;
            float outc = (sW[c] * S0[h] + sW[32 + c] * S1[h]) * r[h];
            float v2 = outc + sB[c];
            v2 = v2 > 0.f ? v2 : __expf(v2) - 1.f;  // elu
            h20 = fmaf(v2, sW2[2 * c], h20);
            h21 = fmaf(v2, sW2[2 * c + 1], h21);
        }
        int n = dbase + t;
        h2[n] = make_float2(h20, h21);
        al2d[n] = h20 * sA2[2] + h21 * sA2[3];
    }
}

// ==================== layer 2: per-bucket LDS accumulation (1 head) ====================
__global__ __launch_bounds__(1024) void agg2_bucket(
        const int* __restrict__ pairs, const int* __restrict__ bcur,
        const float2* __restrict__ h2, const float* __restrict__ al2d,
        const float* __restrict__ as2, const float* __restrict__ b2,
        float2* __restrict__ out, int N) {
    __shared__ float sAld2[BK];
    __shared__ float sAcc[3 * BK];       // [d]=wsum, +BK=ax, +2*BK=ay
    int t = threadIdx.x;
    int b = blockIdx.x;
    int dbase = b << BK_BITS;
    int ndst = min(BK, N - dbase);
    float a0 = as2[0], a1 = as2[1];

    // ---- phase A: self-loop init ----
    if (t < ndst) {
        float2 hv = h2[dbase + t];
        float ald = al2d[dbase + t];
        sAld2[t] = ald;
        float e = lrelu(fmaf(hv.x, a0, fmaf(hv.y, a1, ald)));
        float w = __expf(fminf(e, 80.f));
        sAcc[t] = w;
        sAcc[BK + t] = w * hv.x;
        sAcc[2 * BK + t] = w * hv.y;
    }
    __syncthreads();

    // ---- phase B: stream pairs ----
    int lo = b * CAP, hi = bcur[b];
    for (int base = lo + (t << 2); base < hi; base += 4096) {
        int4 p4 = *(const int4*)(pairs + base);
        int pv[4] = {p4.x, p4.y, p4.z, p4.w};
        int nlive = min(hi - base, 4);
        float2 hv[4];
#pragma unroll
        for (int k = 0; k < 4; k++) {
            int s = (k < nlive) ? (pv[k] & SMASK) : 0;
            hv[k] = h2[s];
        }
#pragma unroll
        for (int k = 0; k < 4; k++) {
            if (k < nlive) {
                int dl = pv[k] >> SBITS;
                float e = lrelu(fmaf(hv[k].x, a0, fmaf(hv[k].y, a1, sAld2[dl])));
                float w = __expf(fminf(e, 80.f));
                unsafeAtomicAdd(&sAcc[dl], w);
                unsafeAtomicAdd(&sAcc[BK + dl], w * hv[k].x);
                unsafeAtomicAdd(&sAcc[2 * BK + dl], w * hv[k].y);
            }
        }
    }
    __syncthreads();

    // ---- phase C ----
    if (t < ndst) {
        float inv = 1.f / (sAcc[t] + 1e-16f);
        out[dbase + t] = make_float2(sAcc[BK + t] * inv + b2[0],
                                     sAcc[2 * BK + t] * inv + b2[1]);
    }
}

extern "C" void kernel_launch(void* const* d_in, const int* in_sizes, int n_in,
                              void* d_out, int out_size, void* d_ws, size_t ws_size,
                              hipStream_t stream) {
    const float* x     = (const float*)d_in[0];
    const int*   eidx  = (const int*)d_in[1];
    const float* W1    = (const float*)d_in[3];
    const float* asrc1 = (const float*)d_in[4];
    const float* adst1 = (const float*)d_in[5];
    const float* b1    = (const float*)d_in[6];
    const float* W2    = (const float*)d_in[7];
    const float* asrc2 = (const float*)d_in[8];
    const float* adst2 = (const float*)d_in[9];
    const float* b2    = (const float*)d_in[10];

    const int N = in_sizes[0] / 2;   // 100000 (< 2^17 for packing)
    const int E = in_sizes[1] / 2;   // 3200000
    const int* src = eidx;
    const int* dst = eidx + E;
    const int NB = (N + BK - 1) >> BK_BITS;   // 196

    // -------- workspace layout --------
    float* w = (float*)d_ws;
    float2* h2    = (float2*)w;                 // 2N floats
    float*  al2d  = w + 2 * (size_t)N;          // N floats (3N total, 16B-aligned end)
    int* ip       = (int*)(w + 3 * (size_t)N);
    int* bcur     = ip;                         // NB (pad to 256 for alignment)
    int* pairs    = ip + 256;                   // NB*CAP, 16B-aligned

    const int B = 256;
    int E4 = E >> 2;
    int gS = (E4 + 1023) / 1024;        // 4096 edges per block

    init_bcur<<<1, B, 0, stream>>>(bcur, NB);
    bucket_scatter<<<gS, B, 0, stream>>>(src, dst, bcur, pairs, E);
    agg1_bucket<<<NB, 1024, 0, stream>>>(pairs, bcur, (const float2*)x,
                                         W1, asrc1, adst1, b1, W2, asrc2, adst2,
                                         h2, al2d, N);
    agg2_bucket<<<NB, 1024, 0, stream>>>(pairs, bcur, (const float2*)h2, al2d,
                                         asrc2, b2, (float2*)d_out, N);
}

// Round 3
// 447.870 us; speedup vs baseline: 1.0021x; 1.0021x over previous
//
#include <hip/hip_runtime.h>
#include <math.h>

#define NEG_SLOPE 0.2f
#define BK_BITS 9
#define BK (1 << BK_BITS)     // 512 dst per bucket -> NB = 196 buckets
#define SBITS 17              // bits for src id (N=100000 < 2^17)
#define SMASK ((1 << SBITS) - 1)
#define CAP 20480             // pairs capacity per bucket (mean 16327, +32 sigma)

__device__ __forceinline__ float lrelu(float x) { return x > 0.f ? x : NEG_SLOPE * x; }

// LDS float atomic add -> ds_add_f32 (no-return). Workgroup scope, relaxed.
// (unsafeAtomicAdd on a shared pointer lowered to flat atomics = 100x slower; R1 lesson.)
__device__ __forceinline__ void lds_fadd(float* p, float v) {
    (void)__hip_atomic_fetch_add(p, v, __ATOMIC_RELAXED, __HIP_MEMORY_SCOPE_WORKGROUP);
}

// ==================== init bucket cursors ====================
__global__ void init_bcur(int* __restrict__ bcur, int NB) {
    int i = threadIdx.x;
    if (i < NB) bcur[i] = i * CAP;
}

// ==================== LDS-staged bucketed scatter (unchanged, proven) ====================
__global__ __launch_bounds__(256) void bucket_scatter(const int* __restrict__ src,
                                                      const int* __restrict__ dst,
                                                      int* __restrict__ bcur,
                                                      int* __restrict__ pairs, int E) {
    __shared__ int cnt[256], sc[256], off[256], cur[256], gbase[256];
    __shared__ int lpair[4096];
    __shared__ unsigned char lbkt[4096];
    int t = threadIdx.x;
    cnt[t] = 0;
    __syncthreads();

    int E4 = E >> 2;
    const int4* src4 = (const int4*)src;
    const int4* dst4 = (const int4*)dst;
    int base4 = blockIdx.x * 1024;
    int4 d4[4], s4[4];
    bool val[4];
#pragma unroll
    for (int k = 0; k < 4; k++) {
        int i4 = base4 + k * 256 + t;
        val[k] = (i4 < E4);
        if (val[k]) {
            d4[k] = dst4[i4];
            s4[k] = src4[i4];
            atomicAdd(&cnt[d4[k].x >> BK_BITS], 1);
            atomicAdd(&cnt[d4[k].y >> BK_BITS], 1);
            atomicAdd(&cnt[d4[k].z >> BK_BITS], 1);
            atomicAdd(&cnt[d4[k].w >> BK_BITS], 1);
        }
    }
    int dt = -1, st = 0;
    if (blockIdx.x == gridDim.x - 1) {
        int e = (E4 << 2) + t;
        if (e < E) { dt = dst[e]; st = src[e]; atomicAdd(&cnt[dt >> BK_BITS], 1); }
    }
    __syncthreads();

    sc[t] = cnt[t];
    __syncthreads();
    for (int o = 1; o < 256; o <<= 1) {
        int u = (t >= o) ? sc[t - o] : 0;
        __syncthreads();
        sc[t] += u;
        __syncthreads();
    }
    int excl = (t == 0) ? 0 : sc[t - 1];
    off[t] = excl;
    cur[t] = excl;
    if (cnt[t] > 0) gbase[t] = atomicAdd(&bcur[t], cnt[t]);
    __syncthreads();
    int total = sc[255];

#pragma unroll
    for (int k = 0; k < 4; k++) {
        if (val[k]) {
            int b, slot;
            b = d4[k].x >> BK_BITS; slot = atomicAdd(&cur[b], 1);
            lpair[slot] = ((d4[k].x & (BK - 1)) << SBITS) | s4[k].x; lbkt[slot] = (unsigned char)b;
            b = d4[k].y >> BK_BITS; slot = atomicAdd(&cur[b], 1);
            lpair[slot] = ((d4[k].y & (BK - 1)) << SBITS) | s4[k].y; lbkt[slot] = (unsigned char)b;
            b = d4[k].z >> BK_BITS; slot = atomicAdd(&cur[b], 1);
            lpair[slot] = ((d4[k].z & (BK - 1)) << SBITS) | s4[k].z; lbkt[slot] = (unsigned char)b;
            b = d4[k].w >> BK_BITS; slot = atomicAdd(&cur[b], 1);
            lpair[slot] = ((d4[k].w & (BK - 1)) << SBITS) | s4[k].w; lbkt[slot] = (unsigned char)b;
        }
    }
    if (dt >= 0) {
        int b = dt >> BK_BITS;
        int slot = atomicAdd(&cur[b], 1);
        lpair[slot] = ((dt & (BK - 1)) << SBITS) | st; lbkt[slot] = (unsigned char)b;
    }
    __syncthreads();

    for (int i = t; i < total; i += 256) {
        int b = lbkt[i];
        pairs[gbase[b] + (i - off[b])] = lpair[i];
    }
}

// ==================== fused layer1: per-bucket LDS accumulation ====================
// One block per bucket of 512 dsts. State per dst: al_dst[4] + {Sw,S0,S1}[4 heads]
// = 16 floats -> 32KB LDS. Pairs streamed once; ds_add_f32 scatter-accumulate.
// Self-loop folded into accumulator init. Epilogue fuses W1 -> +b1 -> ELU -> W2.
__global__ __launch_bounds__(1024) void agg1_bucket(
        const int* __restrict__ pairs, const int* __restrict__ bcur,
        const float2* __restrict__ x2,
        const float* __restrict__ W1, const float* __restrict__ asrc,
        const float* __restrict__ adst, const float* __restrict__ b1,
        const float* __restrict__ W2, const float* __restrict__ as2,
        const float* __restrict__ ad2,
        float2* __restrict__ h2, float* __restrict__ al2d, int N) {
    __shared__ float sW[64], sB[32], sW2[64], sP[4], sQ[4], sPd[4], sQd[4], sA2[4];
    __shared__ float4 sAld[BK];          // per-dst al_dst, 4 heads packed (b128 read)
    __shared__ float sAcc[12 * BK];      // [h*BK+d]=Sw, +4*BK=S0, +8*BK=S1
    int t = threadIdx.x;
    int b = blockIdx.x;
    if (t < 64) { sW[t] = W1[t]; sW2[t] = W2[t]; }
    if (t < 32) sB[t] = b1[t];
    if (t < 2) { sA2[t] = as2[t]; sA2[2 + t] = ad2[t]; }
    if (t < 4) {
        float P = 0.f, Q = 0.f, Pd = 0.f, Qd = 0.f;
#pragma unroll
        for (int k = 0; k < 8; k++) {
            int c = t * 8 + k;
            float a = asrc[c], ad_ = adst[c];
            float w0 = W1[c], w1 = W1[32 + c];
            P += w0 * a; Q += w1 * a;
            Pd += w0 * ad_; Qd += w1 * ad_;
        }
        sP[t] = P; sQ[t] = Q; sPd[t] = Pd; sQd[t] = Qd;
    }
    __syncthreads();

    float rP[4], rQ[4];
#pragma unroll
    for (int h = 0; h < 4; h++) { rP[h] = sP[h]; rQ[h] = sQ[h]; }

    int dbase = b << BK_BITS;
    int ndst = min(BK, N - dbase);

    // ---- phase A: init accumulators with self-loop, stash al_dst ----
    if (t < ndst) {
        float2 xd = x2[dbase + t];
        float ald[4];
#pragma unroll
        for (int h = 0; h < 4; h++) {
            ald[h] = xd.x * sPd[h] + xd.y * sQd[h];
            float e = lrelu(fmaf(xd.x, rP[h], fmaf(xd.y, rQ[h], ald[h])));
            float w = __expf(fminf(e, 80.f));
            sAcc[h * BK + t] = w;
            sAcc[4 * BK + h * BK + t] = w * xd.x;
            sAcc[8 * BK + h * BK + t] = w * xd.y;
        }
        sAld[t] = make_float4(ald[0], ald[1], ald[2], ald[3]);
    }
    __syncthreads();

    // ---- phase B: stream pairs once, LDS scatter-accumulate (ds_add_f32) ----
    int lo = b * CAP, hi = bcur[b];
    for (int base = lo + (t << 2); base < hi; base += 4096) {
        int4 p4 = *(const int4*)(pairs + base);   // 16B-aligned (CAP % 4 == 0)
        int pv[4] = {p4.x, p4.y, p4.z, p4.w};
        int nlive = hi - base; if (nlive > 4) nlive = 4;
        float2 xs[4];
#pragma unroll
        for (int k = 0; k < 4; k++) {
            int s = (k < nlive) ? (pv[k] & SMASK) : 0;
            xs[k] = x2[s];
        }
#pragma unroll
        for (int k = 0; k < 4; k++) {
            if (k < nlive) {
                int dl = pv[k] >> SBITS;
                float4 av = sAld[dl];
                float alh[4] = {av.x, av.y, av.z, av.w};
#pragma unroll
                for (int h = 0; h < 4; h++) {
                    float e = lrelu(fmaf(xs[k].x, rP[h], fmaf(xs[k].y, rQ[h], alh[h])));
                    float w = __expf(fminf(e, 80.f));
                    lds_fadd(&sAcc[h * BK + dl], w);
                    lds_fadd(&sAcc[4 * BK + h * BK + dl], w * xs[k].x);
                    lds_fadd(&sAcc[8 * BK + h * BK + dl], w * xs[k].y);
                }
            }
        }
    }
    __syncthreads();

    // ---- phase C: normalize + fused W1/bias/ELU/W2 epilogue ----
    if (t < ndst) {
        float r[4], S0[4], S1[4];
#pragma unroll
        for (int h = 0; h < 4; h++) {
            float sw = sAcc[h * BK + t];
            r[h] = 1.f / (sw + 1e-16f);
            S0[h] = sAcc[4 * BK + h * BK + t];
            S1[h] = sAcc[8 * BK + h * BK + t];
        }
        float h20 = 0.f, h21 = 0.f;
#pragma unroll
        for (int c = 0; c < 32; c++) {
            int h = c >> 3;
            float outc = (sW[c] * S0[h] + sW[32 + c] * S1[h]) * r[h];
            float v2 = outc + sB[c];
            v2 = v2 > 0.f ? v2 : __expf(v2) - 1.f;  // elu
            h20 = fmaf(v2, sW2[2 * c], h20);
            h21 = fmaf(v2, sW2[2 * c + 1], h21);
        }
        int n = dbase + t;
        h2[n] = make_float2(h20, h21);
        al2d[n] = h20 * sA2[2] + h21 * sA2[3];
    }
}

// ==================== layer 2: per-bucket LDS accumulation (1 head) ====================
__global__ __launch_bounds__(1024) void agg2_bucket(
        const int* __restrict__ pairs, const int* __restrict__ bcur,
        const float2* __restrict__ h2, const float* __restrict__ al2d,
        const float* __restrict__ as2, const float* __restrict__ b2,
        float2* __restrict__ out, int N) {
    __shared__ float sAld2[BK];
    __shared__ float sAcc[3 * BK];       // [d]=wsum, +BK=ax, +2*BK=ay
    int t = threadIdx.x;
    int b = blockIdx.x;
    int dbase = b << BK_BITS;
    int ndst = min(BK, N - dbase);
    float a0 = as2[0], a1 = as2[1];

    // ---- phase A: self-loop init ----
    if (t < ndst) {
        float2 hv = h2[dbase + t];
        float ald = al2d[dbase + t];
        sAld2[t] = ald;
        float e = lrelu(fmaf(hv.x, a0, fmaf(hv.y, a1, ald)));
        float w = __expf(fminf(e, 80.f));
        sAcc[t] = w;
        sAcc[BK + t] = w * hv.x;
        sAcc[2 * BK + t] = w * hv.y;
    }
    __syncthreads();

    // ---- phase B: stream pairs (ds_add_f32) ----
    int lo = b * CAP, hi = bcur[b];
    for (int base = lo + (t << 2); base < hi; base += 4096) {
        int4 p4 = *(const int4*)(pairs + base);
        int pv[4] = {p4.x, p4.y, p4.z, p4.w};
        int nlive = hi - base; if (nlive > 4) nlive = 4;
        float2 hv[4];
#pragma unroll
        for (int k = 0; k < 4; k++) {
            int s = (k < nlive) ? (pv[k] & SMASK) : 0;
            hv[k] = h2[s];
        }
#pragma unroll
        for (int k = 0; k < 4; k++) {
            if (k < nlive) {
                int dl = pv[k] >> SBITS;
                float e = lrelu(fmaf(hv[k].x, a0, fmaf(hv[k].y, a1, sAld2[dl])));
                float w = __expf(fminf(e, 80.f));
                lds_fadd(&sAcc[dl], w);
                lds_fadd(&sAcc[BK + dl], w * hv[k].x);
                lds_fadd(&sAcc[2 * BK + dl], w * hv[k].y);
            }
        }
    }
    __syncthreads();

    // ---- phase C ----
    if (t < ndst) {
        float inv = 1.f / (sAcc[t] + 1e-16f);
        out[dbase + t] = make_float2(sAcc[BK + t] * inv + b2[0],
                                     sAcc[2 * BK + t] * inv + b2[1]);
    }
}

extern "C" void kernel_launch(void* const* d_in, const int* in_sizes, int n_in,
                              void* d_out, int out_size, void* d_ws, size_t ws_size,
                              hipStream_t stream) {
    const float* x     = (const float*)d_in[0];
    const int*   eidx  = (const int*)d_in[1];
    const float* W1    = (const float*)d_in[3];
    const float* asrc1 = (const float*)d_in[4];
    const float* adst1 = (const float*)d_in[5];
    const float* b1    = (const float*)d_in[6];
    const float* W2    = (const float*)d_in[7];
    const float* asrc2 = (const float*)d_in[8];
    const float* adst2 = (const float*)d_in[9];
    const float* b2    = (const float*)d_in[10];

    const int N = in_sizes[0] / 2;   // 100000 (< 2^17 for packing)
    const int E = in_sizes[1] / 2;   // 3200000
    const int* src = eidx;
    const int* dst = eidx + E;
    const int NB = (N + BK - 1) >> BK_BITS;   // 196

    // -------- workspace layout --------
    float* w = (float*)d_ws;
    float2* h2    = (float2*)w;                 // 2N floats
    float*  al2d  = w + 2 * (size_t)N;          // N floats
    int* ip       = (int*)(w + 3 * (size_t)N);
    int* bcur     = ip;                         // NB (padded to 256 for alignment)
    int* pairs    = ip + 256;                   // NB*CAP, 16B-aligned

    const int B = 256;
    int E4 = E >> 2;
    int gS = (E4 + 1023) / 1024;        // 4096 edges per block

    init_bcur<<<1, B, 0, stream>>>(bcur, NB);
    bucket_scatter<<<gS, B, 0, stream>>>(src, dst, bcur, pairs, E);
    agg1_bucket<<<NB, 1024, 0, stream>>>(pairs, bcur, (const float2*)x,
                                         W1, asrc1, adst1, b1, W2, asrc2, adst2,
                                         h2, al2d, N);
    agg2_bucket<<<NB, 1024, 0, stream>>>(pairs, bcur, (const float2*)h2, al2d,
                                         asrc2, b2, (float2*)d_out, N);
}

// Round 4
// 170.460 us; speedup vs baseline: 2.6329x; 2.6274x over previous
//
#include <hip/hip_runtime.h>
#include <math.h>

#define NEG_SLOPE 0.2f
#define BK_BITS 9
#define BK (1 << BK_BITS)     // 512 dst per bucket -> NB = 196 buckets
#define SBITS 17              // bits for src id (N=100000 < 2^17)
#define SMASK ((1 << SBITS) - 1)
#define CAP 20480             // pairs capacity per bucket (mean 16327, +32 sigma); CAP/1024 = 20
#define PPT2 20               // pairs cached in registers per agg thread (== CAP/1024)
// XOR swizzle for sorted LDS array: breaks bank aliasing from mean-degree-32 list starts.
// Bijective within any 1024-word window (low 5 bits ^= bits 5-9), CAP % 32 == 0.
#define SW(p) ((p) ^ (((p) >> 5) & 31))

__device__ __forceinline__ float lrelu(float x) { return x > 0.f ? x : NEG_SLOPE * x; }

// ==================== init bucket cursors ====================
__global__ void init_bcur(int* __restrict__ bcur, int NB) {
    int i = threadIdx.x;
    if (i < NB) bcur[i] = i * CAP;
}

// ==================== LDS-staged bucketed scatter (unchanged, proven) ====================
__global__ __launch_bounds__(256) void bucket_scatter(const int* __restrict__ src,
                                                      const int* __restrict__ dst,
                                                      int* __restrict__ bcur,
                                                      int* __restrict__ pairs, int E) {
    __shared__ int cnt[256], sc[256], off[256], cur[256], gbase[256];
    __shared__ int lpair[4096];
    __shared__ unsigned char lbkt[4096];
    int t = threadIdx.x;
    cnt[t] = 0;
    __syncthreads();

    int E4 = E >> 2;
    const int4* src4 = (const int4*)src;
    const int4* dst4 = (const int4*)dst;
    int base4 = blockIdx.x * 1024;
    int4 d4[4], s4[4];
    bool val[4];
#pragma unroll
    for (int k = 0; k < 4; k++) {
        int i4 = base4 + k * 256 + t;
        val[k] = (i4 < E4);
        if (val[k]) {
            d4[k] = dst4[i4];
            s4[k] = src4[i4];
            atomicAdd(&cnt[d4[k].x >> BK_BITS], 1);
            atomicAdd(&cnt[d4[k].y >> BK_BITS], 1);
            atomicAdd(&cnt[d4[k].z >> BK_BITS], 1);
            atomicAdd(&cnt[d4[k].w >> BK_BITS], 1);
        }
    }
    int dt = -1, st = 0;
    if (blockIdx.x == gridDim.x - 1) {
        int e = (E4 << 2) + t;
        if (e < E) { dt = dst[e]; st = src[e]; atomicAdd(&cnt[dt >> BK_BITS], 1); }
    }
    __syncthreads();

    sc[t] = cnt[t];
    __syncthreads();
    for (int o = 1; o < 256; o <<= 1) {
        int u = (t >= o) ? sc[t - o] : 0;
        __syncthreads();
        sc[t] += u;
        __syncthreads();
    }
    int excl = (t == 0) ? 0 : sc[t - 1];
    off[t] = excl;
    cur[t] = excl;
    if (cnt[t] > 0) gbase[t] = atomicAdd(&bcur[t], cnt[t]);
    __syncthreads();
    int total = sc[255];

#pragma unroll
    for (int k = 0; k < 4; k++) {
        if (val[k]) {
            int b, slot;
            b = d4[k].x >> BK_BITS; slot = atomicAdd(&cur[b], 1);
            lpair[slot] = ((d4[k].x & (BK - 1)) << SBITS) | s4[k].x; lbkt[slot] = (unsigned char)b;
            b = d4[k].y >> BK_BITS; slot = atomicAdd(&cur[b], 1);
            lpair[slot] = ((d4[k].y & (BK - 1)) << SBITS) | s4[k].y; lbkt[slot] = (unsigned char)b;
            b = d4[k].z >> BK_BITS; slot = atomicAdd(&cur[b], 1);
            lpair[slot] = ((d4[k].z & (BK - 1)) << SBITS) | s4[k].z; lbkt[slot] = (unsigned char)b;
            b = d4[k].w >> BK_BITS; slot = atomicAdd(&cur[b], 1);
            lpair[slot] = ((d4[k].w & (BK - 1)) << SBITS) | s4[k].w; lbkt[slot] = (unsigned char)b;
        }
    }
    if (dt >= 0) {
        int b = dt >> BK_BITS;
        int slot = atomicAdd(&cur[b], 1);
        lpair[slot] = ((dt & (BK - 1)) << SBITS) | st; lbkt[slot] = (unsigned char)b;
    }
    __syncthreads();

    for (int i = t; i < total; i += 256) {
        int b = lbkt[i];
        pairs[gbase[b] + (i - off[b])] = lpair[i];
    }
}

// ==================== fused layer1: in-LDS counting sort + register gather ====================
// One block (1024 thr) per bucket of 512 dsts. NO fp atomics:
//  1) stage pairs in registers (20/thread), int-atomic degree count
//  2) prefix-scan 512 degrees, int-atomic scatter src-ids into sorted LDS list (swizzled)
//  3) 2 lanes per dst walk the contiguous list, accumulate in REGISTERS, shfl combine
//  4) self-loop + fused W1 -> +b1 -> ELU -> W2 epilogue
__global__ __launch_bounds__(1024) void agg1_sortgather(
        const int* __restrict__ pairs, const int* __restrict__ bcur,
        const float2* __restrict__ x2,
        const float* __restrict__ W1, const float* __restrict__ asrc,
        const float* __restrict__ adst, const float* __restrict__ b1,
        const float* __restrict__ W2, const float* __restrict__ as2,
        const float* __restrict__ ad2,
        float2* __restrict__ h2, float* __restrict__ al2d, int N) {
    __shared__ float sW[64], sB[32], sW2[64], sP[4], sQ[4], sPd[4], sQd[4], sA2[4];
    __shared__ int cnt[BK], off[BK], cur[BK];
    __shared__ int sorted[CAP];          // 80 KB
    int t = threadIdx.x;
    int b = blockIdx.x;
    if (t < 64) { sW[t] = W1[t]; sW2[t] = W2[t]; }
    if (t < 32) sB[t] = b1[t];
    if (t < 2) { sA2[t] = as2[t]; sA2[2 + t] = ad2[t]; }
    if (t >= 64 && t < 68) {
        int tt = t - 64;
        float P = 0.f, Q = 0.f, Pd = 0.f, Qd = 0.f;
#pragma unroll
        for (int k = 0; k < 8; k++) {
            int c = tt * 8 + k;
            float a = asrc[c], ad_ = adst[c];
            float w0 = W1[c], w1 = W1[32 + c];
            P += w0 * a; Q += w1 * a;
            Pd += w0 * ad_; Qd += w1 * ad_;
        }
        sP[tt] = P; sQ[tt] = Q; sPd[tt] = Pd; sQd[tt] = Qd;
    }
    if (t < BK) cnt[t] = 0;
    __syncthreads();

    int dbase = b << BK_BITS;
    int ndst = min(BK, N - dbase);
    int lo = b * CAP;
    int hi = min(bcur[b], lo + CAP);

    // ---- 1: stage + count (int ds_add, native-fast) ----
    int myp[PPT2];
#pragma unroll
    for (int k = 0; k < PPT2; k++) {
        int i = lo + t + k * 1024;
        int p = (i < hi) ? pairs[i] : -1;
        myp[k] = p;
        if (p >= 0) atomicAdd(&cnt[p >> SBITS], 1);
    }
    __syncthreads();

    // ---- 2: inclusive prefix scan over BK=512 ----
    if (t < BK) off[t] = cnt[t];
    __syncthreads();
    for (int o = 1; o < BK; o <<= 1) {
        int u = 0;
        if (t < BK && t >= o) u = off[t - o];
        __syncthreads();
        if (t < BK) off[t] += u;
        __syncthreads();
    }
    if (t < BK) cur[t] = off[t] - cnt[t];   // exclusive start
    __syncthreads();

    // ---- scatter src ids into sorted order (int atomics + ds_write) ----
#pragma unroll
    for (int k = 0; k < PPT2; k++) {
        int p = myp[k];
        if (p >= 0) {
            int pos = atomicAdd(&cur[p >> SBITS], 1);
            sorted[SW(pos)] = p & SMASK;
        }
    }
    __syncthreads();

    // ---- 3: gather, 2 lanes per dst ----
    int d = t >> 1, q = t & 1;
    if (d < ndst) {
        int n = dbase + d;
        float rP[4], rQ[4], ald[4];
        float2 xd = x2[n];
#pragma unroll
        for (int h = 0; h < 4; h++) {
            rP[h] = sP[h]; rQ[h] = sQ[h];
            ald[h] = xd.x * sPd[h] + xd.y * sQd[h];
        }
        int deg = cnt[d];
        int start = off[d] - deg;
        float Sw[4] = {0.f, 0.f, 0.f, 0.f};
        float S0[4] = {0.f, 0.f, 0.f, 0.f};
        float S1[4] = {0.f, 0.f, 0.f, 0.f};
        for (int j = q; j < deg; j += 2) {
            int s = sorted[SW(start + j)];
            float2 xs = x2[s];
#pragma unroll
            for (int h = 0; h < 4; h++) {
                float e = lrelu(fmaf(xs.x, rP[h], fmaf(xs.y, rQ[h], ald[h])));
                float w = __expf(fminf(e, 80.f));
                Sw[h] += w;
                S0[h] += w * xs.x;
                S1[h] += w * xs.y;
            }
        }
#pragma unroll
        for (int h = 0; h < 4; h++) {
            Sw[h] += __shfl_xor(Sw[h], 1);
            S0[h] += __shfl_xor(S0[h], 1);
            S1[h] += __shfl_xor(S1[h], 1);
        }
        if (q == 0) {
            // self-loop
#pragma unroll
            for (int h = 0; h < 4; h++) {
                float e = lrelu(fmaf(xd.x, rP[h], fmaf(xd.y, rQ[h], ald[h])));
                float w = __expf(fminf(e, 80.f));
                Sw[h] += w;
                S0[h] += w * xd.x;
                S1[h] += w * xd.y;
            }
            // ---- 4: fused epilogue ----
            float r[4];
#pragma unroll
            for (int h = 0; h < 4; h++) r[h] = 1.f / (Sw[h] + 1e-16f);
            float h20 = 0.f, h21 = 0.f;
#pragma unroll
            for (int c = 0; c < 32; c++) {
                int h = c >> 3;
                float outc = (sW[c] * S0[h] + sW[32 + c] * S1[h]) * r[h];
                float v2 = outc + sB[c];
                v2 = v2 > 0.f ? v2 : __expf(v2) - 1.f;  // elu
                h20 = fmaf(v2, sW2[2 * c], h20);
                h21 = fmaf(v2, sW2[2 * c + 1], h21);
            }
            h2[n] = make_float2(h20, h21);
            al2d[n] = h20 * sA2[2] + h21 * sA2[3];
        }
    }
}

// ==================== layer 2: in-LDS counting sort + register gather (1 head) ====================
__global__ __launch_bounds__(1024) void agg2_sortgather(
        const int* __restrict__ pairs, const int* __restrict__ bcur,
        const float2* __restrict__ h2, const float* __restrict__ al2d,
        const float* __restrict__ as2, const float* __restrict__ b2,
        float2* __restrict__ out, int N) {
    __shared__ int cnt[BK], off[BK], cur[BK];
    __shared__ int sorted[CAP];
    int t = threadIdx.x;
    int b = blockIdx.x;
    int dbase = b << BK_BITS;
    int ndst = min(BK, N - dbase);
    float a0 = as2[0], a1 = as2[1];
    if (t < BK) cnt[t] = 0;
    __syncthreads();

    int lo = b * CAP;
    int hi = min(bcur[b], lo + CAP);

    int myp[PPT2];
#pragma unroll
    for (int k = 0; k < PPT2; k++) {
        int i = lo + t + k * 1024;
        int p = (i < hi) ? pairs[i] : -1;
        myp[k] = p;
        if (p >= 0) atomicAdd(&cnt[p >> SBITS], 1);
    }
    __syncthreads();

    if (t < BK) off[t] = cnt[t];
    __syncthreads();
    for (int o = 1; o < BK; o <<= 1) {
        int u = 0;
        if (t < BK && t >= o) u = off[t - o];
        __syncthreads();
        if (t < BK) off[t] += u;
        __syncthreads();
    }
    if (t < BK) cur[t] = off[t] - cnt[t];
    __syncthreads();

#pragma unroll
    for (int k = 0; k < PPT2; k++) {
        int p = myp[k];
        if (p >= 0) {
            int pos = atomicAdd(&cur[p >> SBITS], 1);
            sorted[SW(pos)] = p & SMASK;
        }
    }
    __syncthreads();

    int d = t >> 1, q = t & 1;
    if (d < ndst) {
        int n = dbase + d;
        float2 hd = h2[n];
        float ald = al2d[n];
        int deg = cnt[d];
        int start = off[d] - deg;
        float wsum = 0.f, ax = 0.f, ay = 0.f;
        for (int j = q; j < deg; j += 2) {
            int s = sorted[SW(start + j)];
            float2 hv = h2[s];
            float e = lrelu(fmaf(hv.x, a0, fmaf(hv.y, a1, ald)));
            float w = __expf(fminf(e, 80.f));
            wsum += w;
            ax = fmaf(w, hv.x, ax);
            ay = fmaf(w, hv.y, ay);
        }
        wsum += __shfl_xor(wsum, 1);
        ax += __shfl_xor(ax, 1);
        ay += __shfl_xor(ay, 1);
        if (q == 0) {
            float e = lrelu(fmaf(hd.x, a0, fmaf(hd.y, a1, ald)));
            float w = __expf(fminf(e, 80.f));
            wsum += w; ax = fmaf(w, hd.x, ax); ay = fmaf(w, hd.y, ay);
            float inv = 1.f / (wsum + 1e-16f);
            out[n] = make_float2(ax * inv + b2[0], ay * inv + b2[1]);
        }
    }
}

extern "C" void kernel_launch(void* const* d_in, const int* in_sizes, int n_in,
                              void* d_out, int out_size, void* d_ws, size_t ws_size,
                              hipStream_t stream) {
    const float* x     = (const float*)d_in[0];
    const int*   eidx  = (const int*)d_in[1];
    const float* W1    = (const float*)d_in[3];
    const float* asrc1 = (const float*)d_in[4];
    const float* adst1 = (const float*)d_in[5];
    const float* b1    = (const float*)d_in[6];
    const float* W2    = (const float*)d_in[7];
    const float* asrc2 = (const float*)d_in[8];
    const float* adst2 = (const float*)d_in[9];
    const float* b2    = (const float*)d_in[10];

    const int N = in_sizes[0] / 2;   // 100000 (< 2^17 for packing)
    const int E = in_sizes[1] / 2;   // 3200000
    const int* src = eidx;
    const int* dst = eidx + E;
    const int NB = (N + BK - 1) >> BK_BITS;   // 196

    // -------- workspace layout --------
    float* w = (float*)d_ws;
    float2* h2    = (float2*)w;                 // 2N floats
    float*  al2d  = w + 2 * (size_t)N;          // N floats
    int* ip       = (int*)(w + 3 * (size_t)N);
    int* bcur     = ip;                         // NB (padded to 256 for alignment)
    int* pairs    = ip + 256;                   // NB*CAP, 16B-aligned

    const int B = 256;
    int E4 = E >> 2;
    int gS = (E4 + 1023) / 1024;        // 4096 edges per block

    init_bcur<<<1, B, 0, stream>>>(bcur, NB);
    bucket_scatter<<<gS, B, 0, stream>>>(src, dst, bcur, pairs, E);
    agg1_sortgather<<<NB, 1024, 0, stream>>>(pairs, bcur, (const float2*)x,
                                             W1, asrc1, adst1, b1, W2, asrc2, adst2,
                                             h2, al2d, N);
    agg2_sortgather<<<NB, 1024, 0, stream>>>(pairs, bcur, (const float2*)h2, al2d,
                                             asrc2, b2, (float2*)d_out, N);
}